// Round 1
// baseline (2191.777 us; speedup 1.0000x reference)
//
#include <hip/hip_runtime.h>

#define N 4096
#define D 10000
#define C 10
#define NB 16          // number of 256-step blocks
#define B 256          // steps per block

// ---- workspace layout (float offsets) ----
#define AM_OFF    0                          // [C*D] = 100000
#define GLOC_OFF  100096                     // [16][256][256] = 1048576
#define S_OFF     (GLOC_OFF + NB*B*B)        // [B*C] = 2560
#define HV2_OFF   (S_OFF + B*C)              // [N]
#define AN_OFF    (HV2_OFF + N)              // [16] running ||am_c||^2
#define ANF_OFF   (AN_OFF + 16)              // [16] final  ||am_c||^2
#define PRED_OFF  (ANF_OFF + 16)             // [N] ints
#define WRONG_OFF (PRED_OFF + N)             // [N] ints
#define MIST_OFF  (WRONG_OFF + N)            // [1] int

// ---------------- build_am: segment-sum via per-column accumulate + atomics ----------------
__global__ __launch_bounds__(256) void build_am_kernel(float* __restrict__ am,
        const float* __restrict__ X, const int* __restrict__ labels){
    int d = blockIdx.x*256 + threadIdx.x;
    if (d >= D) return;
    int i0 = blockIdx.y * (N/32);
    float acc[C];
    #pragma unroll
    for (int c=0;c<C;c++) acc[c]=0.f;
    for (int i=i0; i<i0+(N/32); ++i){
        int lab = labels[i];
        float x = X[(size_t)i*D + d];
        #pragma unroll
        for (int c=0;c<C;c++) acc[c] += (lab==c) ? x : 0.f;
    }
    #pragma unroll
    for (int c=0;c<C;c++) atomicAdd(&am[(size_t)c*D + d], acc[c]);
}

// ---------------- row sum-of-squares of am -> out[c] ----------------
__global__ __launch_bounds__(256) void rownorm2_kernel(const float* __restrict__ am,
        float* __restrict__ out){
    int c = blockIdx.x, t = threadIdx.x;
    float p = 0.f;
    for (int d=t; d<D; d+=256){ float v = am[(size_t)c*D+d]; p += v*v; }
    #pragma unroll
    for (int off=32; off>=1; off>>=1) p += __shfl_down(p, off);
    __shared__ float wsum[4];
    int wid = t>>6, lane = t&63;
    if (lane==0) wsum[wid]=p;
    __syncthreads();
    if (t==0) out[c] = wsum[0]+wsum[1]+wsum[2]+wsum[3];
}

// ---------------- block-diagonal Gram tiles (fp32, LDS-tiled, K-split, atomic accumulate) ----
__global__ __launch_bounds__(256) void gram_kernel(const float* __restrict__ X,
        float* __restrict__ Gloc){
    __shared__ float Asm[32][68];   // transposed: [dd][row], pad 68 keeps float4 align, no read conflicts
    __shared__ float Bsm[32][68];
    int bx = blockIdx.x;
    int k  = blockIdx.y;
    int p  = bx % 10;               // upper-triangle 64x64 tile pair
    int z  = bx / 10;               // K-split 0..7
    int ti = (p<4)?0:(p<7)?1:(p<9)?2:3;
    int st = (ti==0)?0:(ti==1)?4:(ti==2)?7:9;
    int tj = ti + (p - st);
    int rowA = k*B + ti*64;
    int rowB = k*B + tj*64;
    int t = threadIdx.x;
    int tx = t & 15, ty = t >> 4;
    float acc[4][4];
    #pragma unroll
    for (int i=0;i<4;i++)
        #pragma unroll
        for (int j=0;j<4;j++) acc[i][j]=0.f;

    for (int ch = z; ch*32 < D; ch += 8){
        int dbase = ch*32;
        int valid = D - dbase; if (valid > 32) valid = 32;
        for (int idx = t; idx < 64*32; idx += 256){
            int dd = idx & 31, r = idx >> 5;
            float a = 0.f, b = 0.f;
            if (dd < valid){
                a = X[(size_t)(rowA + r)*D + dbase + dd];
                b = X[(size_t)(rowB + r)*D + dbase + dd];
            }
            Asm[dd][r] = a; Bsm[dd][r] = b;
        }
        __syncthreads();
        #pragma unroll 4
        for (int dd=0; dd<32; ++dd){
            const float4 av = *(const float4*)&Asm[dd][ty*4];
            const float4 bv = *(const float4*)&Bsm[dd][tx*4];
            float a4[4] = {av.x, av.y, av.z, av.w};
            float b4[4] = {bv.x, bv.y, bv.z, bv.w};
            #pragma unroll
            for (int i=0;i<4;i++)
                #pragma unroll
                for (int j=0;j<4;j++) acc[i][j] += a4[i]*b4[j];
        }
        __syncthreads();
    }
    float* G = Gloc + (size_t)k*B*B;
    int abase = ti*64 + ty*4;
    int bbase = tj*64 + tx*4;
    #pragma unroll
    for (int i=0;i<4;i++)
        #pragma unroll
        for (int j=0;j<4;j++)
            atomicAdd(&G[(abase+i)*B + (bbase+j)], acc[i][j]);
}

// ---------------- S[j][c] = am_c . hv_j (+ fused ||hv||^2) for one 256-block ----------------
__global__ __launch_bounds__(256) void s_kernel(const float* __restrict__ am,
        const float* __restrict__ X, float* __restrict__ S, float* __restrict__ hv2, int k){
    int j = blockIdx.x;
    int gj = k*B + j;
    int t = threadIdx.x;
    const float* xr = X + (size_t)gj*D;
    float p[C+1];
    #pragma unroll
    for (int v=0;v<C+1;v++) p[v]=0.f;
    for (int d=t; d<D; d+=256){
        float x = xr[d];
        p[C] += x*x;
        #pragma unroll
        for (int c=0;c<C;c++) p[c] += x * am[(size_t)c*D + d];
    }
    __shared__ float red[(C+1)*4];
    int wid=t>>6, lane=t&63;
    #pragma unroll
    for (int v=0; v<C+1; ++v){
        float x = p[v];
        #pragma unroll
        for (int off=32; off>=1; off>>=1) x += __shfl_down(x, off);
        if (lane==0) red[v*4+wid] = x;
    }
    __syncthreads();
    if (t < C+1){
        float r = red[t*4+0]+red[t*4+1]+red[t*4+2]+red[t*4+3];
        if (t < C) S[j*C + t] = r;
        else hv2[gj] = r;
    }
}

// ---------------- sequential 256-step replay: single wave, all state in registers ----------
__global__ __launch_bounds__(64) void seq_kernel(const float* __restrict__ S,
        const float* __restrict__ G,        // this block's [256][256] Gram
        const float* __restrict__ hv2, const int* __restrict__ labels,
        float* __restrict__ amnorm2, int* __restrict__ predArr, int* __restrict__ wrongArr,
        int* __restrict__ mistakes, int k){
    int lane = threadIdx.x;
    int base = k*B;
    float s[4][C];
    float h2o[4]; int labo[4];
    #pragma unroll
    for (int q=0;q<4;q++){
        int j = q*64 + lane;
        #pragma unroll
        for (int c=0;c<C;c++) s[q][c] = S[j*C+c];
        h2o[q] = hv2[base + j];
        labo[q] = labels[base + j];
    }
    float an[C], rstd[C];
    #pragma unroll
    for (int c=0;c<C;c++){ an[c] = amnorm2[c]; rstd[c] = rsqrtf(an[c]); }

    int mycnt = 0;
    int myPred[4], myWrong[4];
    float g[4], gn[4];
    #pragma unroll
    for (int sl=0; sl<4; sl++) gn[sl] = G[0*B + sl*64 + lane];   // prefetch row 0

    #pragma unroll
    for (int q=0;q<4;q++){
        myPred[q]=0; myWrong[q]=0;
        for (int jj=0;jj<64;jj++){
            int j = q*64+jj;
            #pragma unroll
            for (int sl=0;sl<4;sl++) g[sl]=gn[sl];
            if (j+1 < B){
                #pragma unroll
                for (int sl=0;sl<4;sl++) gn[sl] = G[(size_t)(j+1)*B + sl*64 + lane];
            }
            // broadcast owner's state (all lanes then compute redundantly -> uniform branch)
            float sb[C];
            #pragma unroll
            for (int c=0;c<C;c++) sb[c] = __shfl(s[q][c], jj);
            float h2b = __shfl(h2o[q], jj);
            int  labb = __shfl(labo[q], jj);
            // argmax of sb[c]*rstd[c]  (|hv| scale and EPS never change the argmax)
            float best = sb[0]*rstd[0]; int bi=0; float braw = sb[0];
            #pragma unroll
            for (int c=1;c<C;c++){ float v = sb[c]*rstd[c]; if (v>best){best=v;bi=c;braw=sb[c];} }
            int wrong = (bi != labb) ? 1 : 0;
            if (lane == jj){ myPred[q]=bi; myWrong[q]=wrong; }
            if (wrong){
                mycnt++;
                float slv = sb[0];
                #pragma unroll
                for (int c=1;c<C;c++) slv = (c==labb)? sb[c] : slv;
                float anp = an[0], anl = an[0];
                #pragma unroll
                for (int c=1;c<C;c++){ anp = (c==bi)? an[c]:anp; anl = (c==labb)? an[c]:anl; }
                if (bi==0) anp = an[0];
                if (labb==0) anl = an[0];
                float anp_new = anp - 2.f*braw + h2b;   // ||am_pred - hv||^2
                float anl_new = anl + 2.f*slv + h2b;    // ||am_lab  + hv||^2
                float rp = rsqrtf(anp_new), rl = rsqrtf(anl_new);
                #pragma unroll
                for (int c=0;c<C;c++){
                    an[c]   = (c==bi)? anp_new : (c==labb)? anl_new : an[c];
                    rstd[c] = (c==bi)? rp      : (c==labb)? rl      : rstd[c];
                }
                // propagate to all future in-block dots: s[j'] += sign_c * G[j][j']
                #pragma unroll
                for (int c=0;c<C;c++){
                    float sg = (c==bi)? -1.f : (c==labb)? 1.f : 0.f;
                    #pragma unroll
                    for (int sl=0;sl<4;sl++) s[sl][c] += sg * g[sl];
                }
            }
        }
    }
    #pragma unroll
    for (int q=0;q<4;q++){
        predArr[base + q*64 + lane]  = myPred[q];
        wrongArr[base + q*64 + lane] = myWrong[q];
    }
    if (lane==0){
        atomicAdd(mistakes, mycnt);
        #pragma unroll
        for (int c=0;c<C;c++) amnorm2[c] = an[c];
    }
}

// ---------------- fold the block's +/-hv corrections into am ----------------
__global__ __launch_bounds__(256) void apply_kernel(float* __restrict__ am,
        const float* __restrict__ X, const int* __restrict__ labels,
        const int* __restrict__ predA, const int* __restrict__ wrongA, int k){
    int d = blockIdx.x*256 + threadIdx.x;
    bool act = d < D;
    float delta[C];
    #pragma unroll
    for (int c=0;c<C;c++) delta[c]=0.f;
    int j0 = blockIdx.y*32;
    for (int j=j0;j<j0+32;j++){
        int gj = k*B+j;
        if (wrongA[gj]){                      // wave-uniform branch
            float x = act ? X[(size_t)gj*D + d] : 0.f;
            int p = predA[gj], l = labels[gj];
            #pragma unroll
            for (int c=0;c<C;c++) delta[c] += (c==p)? -x : (c==l)? x : 0.f;
        }
    }
    if (act){
        #pragma unroll
        for (int c=0;c<C;c++) if (delta[c]!=0.f) atomicAdd(&am[(size_t)c*D+d], delta[c]);
    }
}

// ---------------- final predict: argmax_c (x_i . am_c) * rsqrt(||am_c||^2) ----------------
__global__ __launch_bounds__(256) void predict_kernel(const float* __restrict__ am,
        const float* __restrict__ X, const float* __restrict__ anf, float* __restrict__ outPred){
    int i = blockIdx.x, t = threadIdx.x;
    const float* xr = X + (size_t)i*D;
    float p[C];
    #pragma unroll
    for (int c=0;c<C;c++) p[c]=0.f;
    for (int d=t; d<D; d+=256){
        float x = xr[d];
        #pragma unroll
        for (int c=0;c<C;c++) p[c] += x * am[(size_t)c*D + d];
    }
    __shared__ float red[C*4];
    int wid=t>>6, lane=t&63;
    #pragma unroll
    for (int v=0; v<C; ++v){
        float x = p[v];
        #pragma unroll
        for (int off=32; off>=1; off>>=1) x += __shfl_down(x, off);
        if (lane==0) red[v*4+wid] = x;
    }
    __syncthreads();
    if (t==0){
        float best = -3.4e38f; int bi = 0;
        #pragma unroll
        for (int c=0;c<C;c++){
            float dot = red[c*4+0]+red[c*4+1]+red[c*4+2]+red[c*4+3];
            float v = dot * rsqrtf(anf[c]);
            if (v > best){ best = v; bi = c; }
        }
        outPred[i] = (float)bi;
    }
}

// ---------------- am copy + mistakes scalar ----------------
__global__ __launch_bounds__(256) void finalize_kernel(const float* __restrict__ am,
        const int* __restrict__ mistakes, float* __restrict__ out){
    int i = blockIdx.x*256 + threadIdx.x;
    if (i < C*D) out[i] = am[i];
    if (i == 0) out[C*D + N] = (float)(*mistakes);
}

extern "C" void kernel_launch(void* const* d_in, const int* in_sizes, int n_in,
                              void* d_out, int out_size, void* d_ws, size_t ws_size,
                              hipStream_t stream){
    const float* X      = (const float*)d_in[0];
    const int*   labels = (const int*)d_in[1];
    float* ws   = (float*)d_ws;
    float* am   = ws + AM_OFF;
    float* Gloc = ws + GLOC_OFF;
    float* S    = ws + S_OFF;
    float* hv2  = ws + HV2_OFF;
    float* an   = ws + AN_OFF;
    float* anf  = ws + ANF_OFF;
    int*   predA  = (int*)(ws + PRED_OFF);
    int*   wrongA = (int*)(ws + WRONG_OFF);
    int*   mist   = (int*)(ws + MIST_OFF);
    float* out = (float*)d_out;

    hipMemsetAsync(am,   0, (size_t)C*D*sizeof(float), stream);
    hipMemsetAsync(Gloc, 0, (size_t)NB*B*B*sizeof(float), stream);
    hipMemsetAsync(mist, 0, sizeof(int), stream);

    build_am_kernel<<<dim3(40,32), 256, 0, stream>>>(am, X, labels);
    rownorm2_kernel<<<C, 256, 0, stream>>>(am, an);
    gram_kernel<<<dim3(80,NB), 256, 0, stream>>>(X, Gloc);

    for (int k=0;k<NB;k++){
        s_kernel<<<B, 256, 0, stream>>>(am, X, S, hv2, k);
        seq_kernel<<<1, 64, 0, stream>>>(S, Gloc + (size_t)k*B*B, hv2, labels,
                                         an, predA, wrongA, mist, k);
        apply_kernel<<<dim3(40,8), 256, 0, stream>>>(am, X, labels, predA, wrongA, k);
    }

    rownorm2_kernel<<<C, 256, 0, stream>>>(am, anf);
    predict_kernel<<<N, 256, 0, stream>>>(am, X, anf, out + (size_t)C*D);
    finalize_kernel<<<(C*D + 255)/256 + 1, 256, 0, stream>>>(am, mist, out);
}